// Round 4
// baseline (14993.333 us; speedup 1.0000x reference)
//
#include <hip/hip_runtime.h>
#include <math.h>

#define CHUNK 64          // batch chunk per pipeline pass (4 passes of 64 = 256)
#define NCHUNKS 4

// ---------------------------------------------------------------------------
// Direct conv, NCHW, thread owns 4 spatial positions x CCH output channels.
// Weights staged in LDS as wl[ci*K*K + ky*K + kx][cc] (cc innermost -> float4
// broadcast reads). x read from global (L1/L2 resident), guarded with 0-fill.
// grid = CB * PTILES * (COUT/CCH); block = 256.
// ---------------------------------------------------------------------------
template<int CIN, int COUT, int K, int S, int PAD, int HIN, int WIN,
         int HOUT, int WOUT, bool RELU, int CCH>
__global__ __launch_bounds__(256, 3)
void conv_fwd(const float* __restrict__ x, const float* __restrict__ w,
              const float* __restrict__ bias, float* __restrict__ out) {
  constexpr int NPOS = HOUT * WOUT;
  constexpr int PTILES = NPOS / 1024;
  constexpr int NCH = COUT / CCH;
  constexpr int RSTEP = 256 / WOUT;           // row spacing of owned positions
  constexpr int ROWS_PER_TILE = 1024 / WOUT;
  static_assert(NPOS % 1024 == 0, "pos tiling");
  static_assert(COUT % CCH == 0, "co tiling");

  int bid = blockIdx.x;
  int cchunk = bid % NCH;
  int ptile = (bid / NCH) % PTILES;
  int n = bid / (NCH * PTILES);
  int co0 = cchunk * CCH;

  __shared__ float wl[CIN * K * K][CCH];
  for (int i = threadIdx.x; i < CIN * K * K * CCH; i += 256) {
    int cc = i & (CCH - 1);
    int tap = i / CCH;
    wl[tap][cc] = w[(size_t)(co0 + cc) * (CIN * K * K) + tap];
  }
  __syncthreads();

  int t = threadIdx.x;
  int sx = t % WOUT;
  int syb = ptile * ROWS_PER_TILE + t / WOUT;

  float acc[4][CCH];
#pragma unroll
  for (int j = 0; j < 4; j++)
#pragma unroll
    for (int c = 0; c < CCH; c++) acc[j][c] = 0.f;

  const float* xn = x + (size_t)n * CIN * HIN * WIN;
  int ix0 = sx * S - PAD;

  for (int ci = 0; ci < CIN; ci++) {
    const float* xc = xn + (size_t)ci * HIN * WIN;
#pragma unroll
    for (int ky = 0; ky < K; ky++) {
#pragma unroll
      for (int kx = 0; kx < K; kx++) {
        int ix = ix0 + kx;
        bool xok = (unsigned)ix < WIN;
        float xv[4];
#pragma unroll
        for (int j = 0; j < 4; j++) {
          int iy = (syb + j * RSTEP) * S - PAD + ky;
          bool ok = xok && ((unsigned)iy < HIN);
          xv[j] = ok ? xc[iy * WIN + ix] : 0.f;
        }
        const float* wr = &wl[ci * K * K + ky * K + kx][0];
#pragma unroll
        for (int c = 0; c < CCH; c += 4) {
          float4 wv = *(const float4*)(wr + c);
#pragma unroll
          for (int j = 0; j < 4; j++) {
            acc[j][c + 0] = fmaf(xv[j], wv.x, acc[j][c + 0]);
            acc[j][c + 1] = fmaf(xv[j], wv.y, acc[j][c + 1]);
            acc[j][c + 2] = fmaf(xv[j], wv.z, acc[j][c + 2]);
            acc[j][c + 3] = fmaf(xv[j], wv.w, acc[j][c + 3]);
          }
        }
      }
    }
  }

#pragma unroll
  for (int j = 0; j < 4; j++) {
    int sy = syb + j * RSTEP;
    float* op = out + (((size_t)n * COUT + co0) * HOUT + sy) * WOUT + sx;
#pragma unroll
    for (int c = 0; c < CCH; c++) {
      float v = acc[j][c] + bias[co0 + c];
      if (RELU) v = fmaxf(v, 0.f);
      op[(size_t)c * HOUT * WOUT] = v;
    }
  }
}

// ---------------------------------------------------------------------------
// Transposed conv k=4 s=2 p=1 (torch weight layout [Cin,Cout,4,4]), gather
// form, parity-decomposed: blocks handle one (oy%2, ox%2) subgrid so the
// valid (ky,kx) set is uniform and input reads stay coalesced.
// Verified: 2*iy - 1 + ky == oy for both parities.
// grid = CB * 4parities * PTILES * (COUT/CCH); block = 256.
// ---------------------------------------------------------------------------
template<int CIN, int COUT, int HIN, int WIN, bool RELU, bool SIG, int CCH>
__global__ __launch_bounds__(256, 2)
void convt_fwd(const float* __restrict__ x, const float* __restrict__ w,
               const float* __restrict__ bias, float* __restrict__ out) {
  constexpr int HOUT = 2 * HIN, WOUT = 2 * WIN;
  constexpr int PTILES = (HIN * WIN) / 1024;
  constexpr int NCH = COUT / CCH;
  constexpr int RSTEP = 256 / WIN;
  constexpr int ROWS_PER_TILE = 1024 / WIN;

  int bid = blockIdx.x;
  int cchunk = bid % NCH;
  int ptile = (bid / NCH) % PTILES;
  int par = (bid / (NCH * PTILES)) & 3;
  int n = bid / (NCH * PTILES * 4);
  int py = par >> 1, px = par & 1;
  int co0 = cchunk * CCH;

  __shared__ float wl[CIN * 16][CCH];
  for (int i = threadIdx.x; i < CIN * 16 * CCH; i += 256) {
    int cc = i % CCH;
    int tap = i / CCH;
    int ci = tap >> 4;
    int kk = tap & 15;
    wl[tap][cc] = w[((size_t)ci * COUT + (co0 + cc)) * 16 + kk];
  }
  __syncthreads();

  int t = threadIdx.x;
  int sx = t % WIN;
  int syb = ptile * ROWS_PER_TILE + t / WIN;
  int ky0 = (py + 1) & 1, kx0 = (px + 1) & 1;
  int ay = (py + 1 - ky0) >> 1;   // 0 or 1
  int ax = (px + 1 - kx0) >> 1;

  float acc[4][CCH];
#pragma unroll
  for (int j = 0; j < 4; j++)
#pragma unroll
    for (int c = 0; c < CCH; c++) acc[j][c] = 0.f;

  const float* xn = x + (size_t)n * CIN * HIN * WIN;

  for (int ci = 0; ci < CIN; ci++) {
    const float* xc = xn + (size_t)ci * HIN * WIN;
#pragma unroll
    for (int kyi = 0; kyi < 2; kyi++) {
      int ky = ky0 + 2 * kyi;
      int dy = ay - kyi;
#pragma unroll
      for (int kxi = 0; kxi < 2; kxi++) {
        int kx = kx0 + 2 * kxi;
        int ix = sx + ax - kxi;
        bool xok = (unsigned)ix < WIN;
        float xv[4];
#pragma unroll
        for (int j = 0; j < 4; j++) {
          int iy = syb + j * RSTEP + dy;
          xv[j] = (xok && (unsigned)iy < HIN) ? xc[iy * WIN + ix] : 0.f;
        }
        const float* wr = &wl[ci * 16 + ky * 4 + kx][0];
        if constexpr (CCH >= 4) {
#pragma unroll
          for (int c = 0; c < CCH; c += 4) {
            float4 wv = *(const float4*)(wr + c);
#pragma unroll
            for (int j = 0; j < 4; j++) {
              acc[j][c + 0] = fmaf(xv[j], wv.x, acc[j][c + 0]);
              acc[j][c + 1] = fmaf(xv[j], wv.y, acc[j][c + 1]);
              acc[j][c + 2] = fmaf(xv[j], wv.z, acc[j][c + 2]);
              acc[j][c + 3] = fmaf(xv[j], wv.w, acc[j][c + 3]);
            }
          }
        } else {
          float wv = wr[0];
#pragma unroll
          for (int j = 0; j < 4; j++) acc[j][0] = fmaf(xv[j], wv, acc[j][0]);
        }
      }
    }
  }

#pragma unroll
  for (int j = 0; j < 4; j++) {
    int sy = syb + j * RSTEP;
    int oy = 2 * sy + py;
    int ox = 2 * sx + px;
    float* op = out + (((size_t)n * COUT + co0) * HOUT + oy) * WOUT + ox;
#pragma unroll
    for (int c = 0; c < CCH; c++) {
      float v = acc[j][c] + bias[co0 + c];
      if (RELU) v = fmaxf(v, 0.f);
      if (SIG) v = 1.f / (1.f + expf(-v));
      op[(size_t)c * HOUT * WOUT] = v;
    }
  }
}

// ---------------------------------------------------------------------------
// Codebook squared norms, replicating numpy's pairwise sum for n=32:
//   r[j] = ((m[j]+m[8+j])+m[16+j])+m[24+j];  res = ((r0+r1)+(r2+r3))+((r4+r5)+(r6+r7))
// fp contract OFF so mul+add are rounded separately like np.
// ---------------------------------------------------------------------------
__global__ void cbn_prep(const float* __restrict__ cb, float* __restrict__ cbn) {
#pragma clang fp contract(off)
  int k = blockIdx.x * 256 + threadIdx.x;
  if (k < 512) {
    float m[32];
#pragma unroll
    for (int d = 0; d < 32; d++) {
      float c = cb[k * 32 + d];
      m[d] = c * c;
    }
    float r[8];
#pragma unroll
    for (int j = 0; j < 8; j++)
      r[j] = ((m[j] + m[8 + j]) + m[16 + j]) + m[24 + j];
    cbn[k] = ((r[0] + r[1]) + (r[2] + r[3])) + ((r[4] + r[5]) + (r[6] + r[7]));
  }
}

// ---------------------------------------------------------------------------
// VQ, replicating the numpy reference's fp32 arithmetic:
//   dists = ||z||^2 + ||c||^2 - 2*(z.c)
// ||z||^2 via numpy pairwise order (see cbn_prep); z.c as ONE sequential FMA
// chain over d (BLAS k-loop order); dist assembled (zz+cc)-2*dot. The large
// zz term quantizes near-ties exactly like np, so argmin flips vanish.
// Strict < keeps FIRST min (np tie rule). qz gets the straight-through value
// z + (q - z), matching the reference's forward arithmetic.
// 2 pixels/thread; codebook = 64KiB LDS. grid = CB*2; block = 256.
// ---------------------------------------------------------------------------
__global__ __launch_bounds__(256, 2)
void vq_kernel(const float* __restrict__ z, const float* __restrict__ cb,
               const float* __restrict__ cbn, float* __restrict__ qz,
               float* __restrict__ loss) {
  __shared__ float cbl[512][32];
  int tid = threadIdx.x;
  for (int i = tid; i < 16384; i += 256) ((float*)cbl)[i] = cb[i];
  __syncthreads();

  int n = blockIdx.x >> 1;
  int p0 = (blockIdx.x & 1) * 512 + tid;  // pixel index in 32*32 image
  int p1 = p0 + 256;
  const float* zn = z + (size_t)n * 32 * 1024;

  float z0[32], z1[32];
#pragma unroll
  for (int d = 0; d < 32; d++) {
    z0[d] = zn[(size_t)d * 1024 + p0];
    z1[d] = zn[(size_t)d * 1024 + p1];
  }

  // ||z||^2 in numpy pairwise order, no fp contraction
  float zz0, zz1;
  {
#pragma clang fp contract(off)
    float m0[32], m1[32];
#pragma unroll
    for (int d = 0; d < 32; d++) {
      m0[d] = z0[d] * z0[d];
      m1[d] = z1[d] * z1[d];
    }
    float r0[8], r1[8];
#pragma unroll
    for (int j = 0; j < 8; j++) {
      r0[j] = ((m0[j] + m0[8 + j]) + m0[16 + j]) + m0[24 + j];
      r1[j] = ((m1[j] + m1[8 + j]) + m1[16 + j]) + m1[24 + j];
    }
    zz0 = ((r0[0] + r0[1]) + (r0[2] + r0[3])) + ((r0[4] + r0[5]) + (r0[6] + r0[7]));
    zz1 = ((r1[0] + r1[1]) + (r1[2] + r1[3])) + ((r1[4] + r1[5]) + (r1[6] + r1[7]));
  }

  float best0 = 3.4e38f, best1 = 3.4e38f;
  int bk0 = 0, bk1 = 0;
  for (int k4 = 0; k4 < 512; k4 += 4) {
    float4 cn = *(const float4*)(cbn + k4);
    // 8 independent sequential FMA chains (4 codes x 2 pixels)
    float da[4], db[4];
#pragma unroll
    for (int u = 0; u < 4; u++) { da[u] = 0.f; db[u] = 0.f; }
#pragma unroll
    for (int d = 0; d < 32; d += 4) {
#pragma unroll
      for (int u = 0; u < 4; u++) {
        float4 c = *(const float4*)&cbl[k4 + u][d];
        float a = da[u], b = db[u];
        a = fmaf(z0[d + 0], c.x, a);
        a = fmaf(z0[d + 1], c.y, a);
        a = fmaf(z0[d + 2], c.z, a);
        a = fmaf(z0[d + 3], c.w, a);
        b = fmaf(z1[d + 0], c.x, b);
        b = fmaf(z1[d + 1], c.y, b);
        b = fmaf(z1[d + 2], c.z, b);
        b = fmaf(z1[d + 3], c.w, b);
        da[u] = a; db[u] = b;
      }
    }
#pragma unroll
    for (int u = 0; u < 4; u++) {
      float cnu = (u == 0) ? cn.x : (u == 1) ? cn.y : (u == 2) ? cn.z : cn.w;
      float s0, s1;
      {
#pragma clang fp contract(off)
        s0 = (zz0 + cnu) - 2.f * da[u];
        s1 = (zz1 + cnu) - 2.f * db[u];
      }
      int k = k4 + u;
      if (s0 < best0) { best0 = s0; bk0 = k; }
      if (s1 < best1) { best1 = s1; bk1 = k; }
    }
  }

  float lsum = 0.f;
  float* qn = qz + (size_t)n * 32 * 1024;
#pragma unroll
  for (int d = 0; d < 32; d += 4) {
#pragma clang fp contract(off)
    // quant gathered from global (L1-hot 64KB table) to avoid the 64-way LDS
    // bank conflict a column-gather of cbl would cause.
    float4 q0 = *(const float4*)(cb + bk0 * 32 + d);
    float4 q1 = *(const float4*)(cb + bk1 * 32 + d);
    float e;
    e = q0.x - z0[d + 0]; lsum = fmaf(e, e, lsum);
    e = q0.y - z0[d + 1]; lsum = fmaf(e, e, lsum);
    e = q0.z - z0[d + 2]; lsum = fmaf(e, e, lsum);
    e = q0.w - z0[d + 3]; lsum = fmaf(e, e, lsum);
    e = q1.x - z1[d + 0]; lsum = fmaf(e, e, lsum);
    e = q1.y - z1[d + 1]; lsum = fmaf(e, e, lsum);
    e = q1.z - z1[d + 2]; lsum = fmaf(e, e, lsum);
    e = q1.w - z1[d + 3]; lsum = fmaf(e, e, lsum);
    // straight-through forward value: z + (q - z), rounded like the reference
    qn[(size_t)(d + 0) * 1024 + p0] = z0[d + 0] + (q0.x - z0[d + 0]);
    qn[(size_t)(d + 1) * 1024 + p0] = z0[d + 1] + (q0.y - z0[d + 1]);
    qn[(size_t)(d + 2) * 1024 + p0] = z0[d + 2] + (q0.z - z0[d + 2]);
    qn[(size_t)(d + 3) * 1024 + p0] = z0[d + 3] + (q0.w - z0[d + 3]);
    qn[(size_t)(d + 0) * 1024 + p1] = z1[d + 0] + (q1.x - z1[d + 0]);
    qn[(size_t)(d + 1) * 1024 + p1] = z1[d + 1] + (q1.y - z1[d + 1]);
    qn[(size_t)(d + 2) * 1024 + p1] = z1[d + 2] + (q1.z - z1[d + 2]);
    qn[(size_t)(d + 3) * 1024 + p1] = z1[d + 3] + (q1.w - z1[d + 3]);
  }

#pragma unroll
  for (int off = 32; off; off >>= 1) lsum += __shfl_down(lsum, off, 64);
  if ((tid & 63) == 0) atomicAdd(loss, lsum);
}

__global__ void finalize_loss(const float* __restrict__ loss, float* __restrict__ out) {
  if (threadIdx.x == 0) {
    float m = loss[0] / 8388608.f;   // mean over 256*32*32*32 elements
    out[0] = m + 0.26f * m;          // emb_loss + 0.26 * commitment_loss
  }
}

// ---------------------------------------------------------------------------
// Workspace budget (floats), chunk = 64 samples:
//   arena A: 8,388,608  (h1 -> {h3, z, qz} -> d2)
//   arena B: 4,194,304  (h2 -> d1)
//   cbn 512, lossacc 1           total = 12,583,425 fl = 50.3 MB
// ---------------------------------------------------------------------------
extern "C" void kernel_launch(void* const* d_in, const int* in_sizes, int n_in,
                              void* d_out, int out_size, void* d_ws, size_t ws_size,
                              hipStream_t stream) {
  (void)in_sizes; (void)n_in; (void)out_size; (void)ws_size;
  const float* x   = (const float*)d_in[0];
  const float* ew1 = (const float*)d_in[1];
  const float* eb1 = (const float*)d_in[2];
  const float* ew2 = (const float*)d_in[3];
  const float* eb2 = (const float*)d_in[4];
  const float* ew3 = (const float*)d_in[5];
  const float* eb3 = (const float*)d_in[6];
  const float* ew4 = (const float*)d_in[7];
  const float* eb4 = (const float*)d_in[8];
  const float* cb  = (const float*)d_in[9];
  const float* dw1 = (const float*)d_in[10];
  const float* db1 = (const float*)d_in[11];
  const float* tw1 = (const float*)d_in[12];
  const float* tb1 = (const float*)d_in[13];
  const float* tw2 = (const float*)d_in[14];
  const float* tb2 = (const float*)d_in[15];
  float* out = (float*)d_out;

  float* ws = (float*)d_ws;
  float* A = ws;                          // 8,388,608 floats
  float* B = A + 8388608;                 // 4,194,304 floats
  float* cbn = B + 4194304;               // 512
  float* lossacc = cbn + 512;             // 1

  float* h1 = A;
  float* h2 = B;
  float* h3 = A;                          // [0 .. 4,194,304)
  float* z  = A + 4194304;                // [4.2M .. 6.3M)
  float* qz = A + 6291456;                // [6.3M .. 8.4M)
  float* d1 = B;
  float* d2 = A;

  cbn_prep<<<2, 256, 0, stream>>>(cb, cbn);
  (void)hipMemsetAsync(lossacc, 0, 4, stream);

  for (int c = 0; c < NCHUNKS; c++) {
    const float* xc = x + (size_t)c * CHUNK * 128 * 128;      // 1 in-channel
    float* outc = out + (size_t)c * CHUNK * 128 * 128;        // 1 out-channel

    // Encoder
    conv_fwd<1, 32, 4, 2, 1, 128, 128, 64, 64, true, 16>
        <<<CHUNK * 4 * 2, 256, 0, stream>>>(xc, ew1, eb1, h1);
    conv_fwd<32, 64, 4, 2, 1, 64, 64, 32, 32, true, 16>
        <<<CHUNK * 1 * 4, 256, 0, stream>>>(h1, ew2, eb2, h2);
    conv_fwd<64, 64, 3, 1, 1, 32, 32, 32, 32, true, 16>
        <<<CHUNK * 1 * 4, 256, 0, stream>>>(h2, ew3, eb3, h3);
    conv_fwd<64, 32, 1, 1, 0, 32, 32, 32, 32, false, 16>
        <<<CHUNK * 1 * 2, 256, 0, stream>>>(h3, ew4, eb4, z);

    // VQ
    vq_kernel<<<CHUNK * 2, 256, 0, stream>>>(z, cb, cbn, qz, lossacc);

    // Decoder
    conv_fwd<32, 64, 3, 1, 1, 32, 32, 32, 32, true, 16>
        <<<CHUNK * 1 * 4, 256, 0, stream>>>(qz, dw1, db1, d1);
    convt_fwd<64, 32, 32, 32, true, false, 16>
        <<<CHUNK * 4 * 1 * 2, 256, 0, stream>>>(d1, tw1, tb1, d2);
    convt_fwd<32, 1, 64, 64, false, true, 1>
        <<<CHUNK * 4 * 4 * 1, 256, 0, stream>>>(d2, tw2, tb2, outc);
  }

  finalize_loss<<<1, 64, 0, stream>>>(lossacc, out + 4194304);
}

// Round 5
// 1600.271 us; speedup vs baseline: 9.3692x; 9.3692x over previous
//
#include <hip/hip_runtime.h>
#include <math.h>

// ---------------------------------------------------------------------------
// Legacy direct conv (global loads) — kept for conv1 (CIN=1, cheap), conv4
// (1x1). Thread owns 4 positions x CCH channels.
// ---------------------------------------------------------------------------
template<int CIN, int COUT, int K, int S, int PAD, int HIN, int WIN,
         int HOUT, int WOUT, bool RELU, int CCH>
__global__ __launch_bounds__(256, 3)
void conv_fwd(const float* __restrict__ x, const float* __restrict__ w,
              const float* __restrict__ bias, float* __restrict__ out) {
  constexpr int NPOS = HOUT * WOUT;
  constexpr int PTILES = NPOS / 1024;
  constexpr int NCH = COUT / CCH;
  constexpr int RSTEP = 256 / WOUT;
  constexpr int ROWS_PER_TILE = 1024 / WOUT;
  static_assert(NPOS % 1024 == 0, "pos tiling");

  int bid = blockIdx.x;
  int cchunk = bid % NCH;
  int ptile = (bid / NCH) % PTILES;
  int n = bid / (NCH * PTILES);
  int co0 = cchunk * CCH;

  __shared__ float wl[CIN * K * K][CCH];
  for (int i = threadIdx.x; i < CIN * K * K * CCH; i += 256) {
    int cc = i % CCH;
    int tap = i / CCH;
    wl[tap][cc] = w[(size_t)(co0 + cc) * (CIN * K * K) + tap];
  }
  __syncthreads();

  int t = threadIdx.x;
  int sx = t % WOUT;
  int syb = ptile * ROWS_PER_TILE + t / WOUT;

  float acc[4][CCH];
#pragma unroll
  for (int j = 0; j < 4; j++)
#pragma unroll
    for (int c = 0; c < CCH; c++) acc[j][c] = 0.f;

  const float* xn = x + (size_t)n * CIN * HIN * WIN;
  int ix0 = sx * S - PAD;

  for (int ci = 0; ci < CIN; ci++) {
    const float* xc = xn + (size_t)ci * HIN * WIN;
#pragma unroll
    for (int ky = 0; ky < K; ky++) {
#pragma unroll
      for (int kx = 0; kx < K; kx++) {
        int ix = ix0 + kx;
        bool xok = (unsigned)ix < WIN;
        float xv[4];
#pragma unroll
        for (int j = 0; j < 4; j++) {
          int iy = (syb + j * RSTEP) * S - PAD + ky;
          bool ok = xok && ((unsigned)iy < HIN);
          xv[j] = ok ? xc[iy * WIN + ix] : 0.f;
        }
        const float* wr = &wl[ci * K * K + ky * K + kx][0];
        if constexpr (CCH >= 4) {
#pragma unroll
          for (int c = 0; c < CCH; c += 4) {
            float4 wv = *(const float4*)(wr + c);
#pragma unroll
            for (int j = 0; j < 4; j++) {
              acc[j][c + 0] = fmaf(xv[j], wv.x, acc[j][c + 0]);
              acc[j][c + 1] = fmaf(xv[j], wv.y, acc[j][c + 1]);
              acc[j][c + 2] = fmaf(xv[j], wv.z, acc[j][c + 2]);
              acc[j][c + 3] = fmaf(xv[j], wv.w, acc[j][c + 3]);
            }
          }
        } else {
          float wv = wr[0];
#pragma unroll
          for (int j = 0; j < 4; j++) acc[j][0] = fmaf(xv[j], wv, acc[j][0]);
        }
      }
    }
  }

#pragma unroll
  for (int j = 0; j < 4; j++) {
    int sy = syb + j * RSTEP;
    float* op = out + (((size_t)n * COUT + co0) * HOUT + sy) * WOUT + sx;
#pragma unroll
    for (int c = 0; c < CCH; c++) {
      float v = acc[j][c] + bias[co0 + c];
      if (RELU) v = fmaxf(v, 0.f);
      op[(size_t)c * HOUT * WOUT] = v;
    }
  }
}

// ---------------------------------------------------------------------------
// LDS-staged 3x3 s=1 pad=1 ReLU conv on 32x32 images (conv3, dec1).
// Block = one sample x CCH output channels, full image (4 pos/thread).
// Input staged 4 channels (16 KB) at a time; all tap reads hit LDS.
// Accumulation order (ci -> ky -> kx) bitwise-identical to conv_fwd.
// grid = NB * (COUT/CCH).
// ---------------------------------------------------------------------------
template<int CIN, int COUT, int CCH>
__global__ __launch_bounds__(256, 3)
void conv3x3_lds(const float* __restrict__ x, const float* __restrict__ w,
                 const float* __restrict__ bias, float* __restrict__ out) {
  constexpr int NCH = COUT / CCH;
  int bid = blockIdx.x;
  int cchunk = bid % NCH;
  int n = bid / NCH;
  int co0 = cchunk * CCH;

  __shared__ float wl[CIN * 9][CCH];
  __shared__ float xs[4 * 1024];
  for (int i = threadIdx.x; i < CIN * 9 * CCH; i += 256) {
    int cc = i % CCH;
    int tap = i / CCH;
    wl[tap][cc] = w[(size_t)(co0 + cc) * (CIN * 9) + tap];
  }

  int t = threadIdx.x;
  int sx = t & 31;
  int sy0 = t >> 5;

  float acc[4][CCH];
#pragma unroll
  for (int j = 0; j < 4; j++)
#pragma unroll
    for (int c = 0; c < CCH; c++) acc[j][c] = 0.f;

  const float* xn = x + (size_t)n * CIN * 1024;

  for (int cg = 0; cg < CIN / 4; cg++) {
    __syncthreads();
#pragma unroll
    for (int k = 0; k < 4; k++)
      *(float4*)(xs + k * 1024 + t * 4) =
          *(const float4*)(xn + (size_t)(cg * 4 + k) * 1024 + t * 4);
    __syncthreads();

#pragma unroll
    for (int c4 = 0; c4 < 4; c4++) {
      int ci = cg * 4 + c4;
      const float* xc = xs + c4 * 1024;
#pragma unroll
      for (int ky = 0; ky < 3; ky++) {
#pragma unroll
        for (int kx = 0; kx < 3; kx++) {
          int ix = sx + kx - 1;
          bool xok = (unsigned)ix < 32;
          float xv[4];
#pragma unroll
          for (int j = 0; j < 4; j++) {
            int iy = sy0 + j * 8 + ky - 1;
            bool ok = xok && ((unsigned)iy < 32);
            float v = xc[ok ? iy * 32 + ix : 0];
            xv[j] = ok ? v : 0.f;
          }
          const float* wr = &wl[ci * 9 + ky * 3 + kx][0];
#pragma unroll
          for (int c = 0; c < CCH; c += 4) {
            float4 wv = *(const float4*)(wr + c);
#pragma unroll
            for (int j = 0; j < 4; j++) {
              acc[j][c + 0] = fmaf(xv[j], wv.x, acc[j][c + 0]);
              acc[j][c + 1] = fmaf(xv[j], wv.y, acc[j][c + 1]);
              acc[j][c + 2] = fmaf(xv[j], wv.z, acc[j][c + 2]);
              acc[j][c + 3] = fmaf(xv[j], wv.w, acc[j][c + 3]);
            }
          }
        }
      }
    }
  }

#pragma unroll
  for (int j = 0; j < 4; j++) {
    int sy = sy0 + j * 8;
    float* op = out + (((size_t)n * COUT + co0) * 32 + sy) * 32 + sx;
#pragma unroll
    for (int c = 0; c < CCH; c++) {
      float v = acc[j][c] + bias[co0 + c];
      v = fmaxf(v, 0.f);
      op[(size_t)c * 1024] = v;
    }
  }
}

// ---------------------------------------------------------------------------
// LDS-staged 4x4 s=2 pad=1 ReLU conv, 64x64 -> 32x32 (conv2).
// Input staged 1 channel (16 KB) per iteration. grid = NB * (COUT/CCH).
// ---------------------------------------------------------------------------
template<int CIN, int COUT, int CCH>
__global__ __launch_bounds__(256, 3)
void conv4x4s2_lds(const float* __restrict__ x, const float* __restrict__ w,
                   const float* __restrict__ bias, float* __restrict__ out) {
  constexpr int NCH = COUT / CCH;
  int bid = blockIdx.x;
  int cchunk = bid % NCH;
  int n = bid / NCH;
  int co0 = cchunk * CCH;

  __shared__ float wl[CIN * 16][CCH];
  __shared__ float xs[4096];
  for (int i = threadIdx.x; i < CIN * 16 * CCH; i += 256) {
    int cc = i % CCH;
    int tap = i / CCH;
    wl[tap][cc] = w[(size_t)(co0 + cc) * (CIN * 16) + tap];
  }

  int t = threadIdx.x;
  int sx = t & 31;
  int sy0 = t >> 5;
  int ix0 = 2 * sx - 1;

  float acc[4][CCH];
#pragma unroll
  for (int j = 0; j < 4; j++)
#pragma unroll
    for (int c = 0; c < CCH; c++) acc[j][c] = 0.f;

  const float* xn = x + (size_t)n * CIN * 4096;

  for (int ci = 0; ci < CIN; ci++) {
    __syncthreads();
#pragma unroll
    for (int k = 0; k < 4; k++)
      *(float4*)(xs + k * 1024 + t * 4) =
          *(const float4*)(xn + (size_t)ci * 4096 + k * 1024 + t * 4);
    __syncthreads();

#pragma unroll
    for (int ky = 0; ky < 4; ky++) {
#pragma unroll
      for (int kx = 0; kx < 4; kx++) {
        int ix = ix0 + kx;
        bool xok = (unsigned)ix < 64;
        float xv[4];
#pragma unroll
        for (int j = 0; j < 4; j++) {
          int iy = 2 * (sy0 + j * 8) - 1 + ky;
          bool ok = xok && ((unsigned)iy < 64);
          float v = xs[ok ? iy * 64 + ix : 0];
          xv[j] = ok ? v : 0.f;
        }
        const float* wr = &wl[ci * 16 + ky * 4 + kx][0];
#pragma unroll
        for (int c = 0; c < CCH; c += 4) {
          float4 wv = *(const float4*)(wr + c);
#pragma unroll
          for (int j = 0; j < 4; j++) {
            acc[j][c + 0] = fmaf(xv[j], wv.x, acc[j][c + 0]);
            acc[j][c + 1] = fmaf(xv[j], wv.y, acc[j][c + 1]);
            acc[j][c + 2] = fmaf(xv[j], wv.z, acc[j][c + 2]);
            acc[j][c + 3] = fmaf(xv[j], wv.w, acc[j][c + 3]);
          }
        }
      }
    }
  }

#pragma unroll
  for (int j = 0; j < 4; j++) {
    int sy = sy0 + j * 8;
    float* op = out + (((size_t)n * COUT + co0) * 32 + sy) * 32 + sx;
#pragma unroll
    for (int c = 0; c < CCH; c++) {
      float v = acc[j][c] + bias[co0 + c];
      v = fmaxf(v, 0.f);
      op[(size_t)c * 1024] = v;
    }
  }
}

// ---------------------------------------------------------------------------
// LDS-staged transposed conv k=4 s=2 p=1 via parity decomposition (dect1,
// ReLU). Per parity only 4 of 16 taps are live: stage those (16 KB) + 4
// input channels (16 KB). grid = NB * 4 * (COUT/CCH). out is 64x64.
// Accumulation order (ci -> kyi -> kxi) bitwise-identical to convt_fwd.
// ---------------------------------------------------------------------------
template<int CIN, int COUT, int CCH>
__global__ __launch_bounds__(256, 4)
void convt_lds(const float* __restrict__ x, const float* __restrict__ w,
               const float* __restrict__ bias, float* __restrict__ out) {
  constexpr int NCH = COUT / CCH;
  int bid = blockIdx.x;
  int cchunk = bid % NCH;
  int par = (bid / NCH) & 3;
  int n = bid / (NCH * 4);
  int py = par >> 1, px = par & 1;
  int co0 = cchunk * CCH;
  int ky0 = (py + 1) & 1, kx0 = (px + 1) & 1;
  int ay = (py + 1 - ky0) >> 1;
  int ax = (px + 1 - kx0) >> 1;

  __shared__ float wl[CIN * 4][CCH];
  __shared__ float xs[4 * 1024];
  for (int i = threadIdx.x; i < CIN * 4 * CCH; i += 256) {
    int cc = i % CCH;
    int tap = i / CCH;
    int ci = tap >> 2;
    int kyi = (tap >> 1) & 1, kxi = tap & 1;
    int ky = ky0 + 2 * kyi, kx = kx0 + 2 * kxi;
    wl[tap][cc] = w[((size_t)ci * COUT + (co0 + cc)) * 16 + ky * 4 + kx];
  }

  int t = threadIdx.x;
  int sx = t & 31;
  int sy0 = t >> 5;

  float acc[4][CCH];
#pragma unroll
  for (int j = 0; j < 4; j++)
#pragma unroll
    for (int c = 0; c < CCH; c++) acc[j][c] = 0.f;

  const float* xn = x + (size_t)n * CIN * 1024;

  for (int cg = 0; cg < CIN / 4; cg++) {
    __syncthreads();
#pragma unroll
    for (int k = 0; k < 4; k++)
      *(float4*)(xs + k * 1024 + t * 4) =
          *(const float4*)(xn + (size_t)(cg * 4 + k) * 1024 + t * 4);
    __syncthreads();

#pragma unroll
    for (int c4 = 0; c4 < 4; c4++) {
      int ci = cg * 4 + c4;
      const float* xc = xs + c4 * 1024;
#pragma unroll
      for (int kyi = 0; kyi < 2; kyi++) {
        int dy = ay - kyi;
#pragma unroll
        for (int kxi = 0; kxi < 2; kxi++) {
          int ix = sx + ax - kxi;
          bool xok = (unsigned)ix < 32;
          float xv[4];
#pragma unroll
          for (int j = 0; j < 4; j++) {
            int iy = sy0 + j * 8 + dy;
            bool ok = xok && ((unsigned)iy < 32);
            float v = xc[ok ? iy * 32 + ix : 0];
            xv[j] = ok ? v : 0.f;
          }
          const float* wr = &wl[ci * 4 + kyi * 2 + kxi][0];
#pragma unroll
          for (int c = 0; c < CCH; c += 4) {
            float4 wv = *(const float4*)(wr + c);
#pragma unroll
            for (int j = 0; j < 4; j++) {
              acc[j][c + 0] = fmaf(xv[j], wv.x, acc[j][c + 0]);
              acc[j][c + 1] = fmaf(xv[j], wv.y, acc[j][c + 1]);
              acc[j][c + 2] = fmaf(xv[j], wv.z, acc[j][c + 2]);
              acc[j][c + 3] = fmaf(xv[j], wv.w, acc[j][c + 3]);
            }
          }
        }
      }
    }
  }

#pragma unroll
  for (int j = 0; j < 4; j++) {
    int sy = sy0 + j * 8;
    int oy = 2 * sy + py;
    int ox = 2 * sx + px;
    float* op = out + (((size_t)n * COUT + co0) * 64 + oy) * 64 + ox;
#pragma unroll
    for (int c = 0; c < CCH; c++) {
      float v = acc[j][c] + bias[co0 + c];
      v = fmaxf(v, 0.f);
      op[(size_t)c * 4096] = v;
    }
  }
}

// ---------------------------------------------------------------------------
// Legacy transposed conv (global loads) — kept for dect2 (COUT=1, sigmoid).
// ---------------------------------------------------------------------------
template<int CIN, int COUT, int HIN, int WIN, bool RELU, bool SIG, int CCH>
__global__ __launch_bounds__(256, 2)
void convt_fwd(const float* __restrict__ x, const float* __restrict__ w,
               const float* __restrict__ bias, float* __restrict__ out) {
  constexpr int HOUT = 2 * HIN, WOUT = 2 * WIN;
  constexpr int PTILES = (HIN * WIN) / 1024;
  constexpr int NCH = COUT / CCH;
  constexpr int RSTEP = 256 / WIN;
  constexpr int ROWS_PER_TILE = 1024 / WIN;

  int bid = blockIdx.x;
  int cchunk = bid % NCH;
  int ptile = (bid / NCH) % PTILES;
  int par = (bid / (NCH * PTILES)) & 3;
  int n = bid / (NCH * PTILES * 4);
  int py = par >> 1, px = par & 1;
  int co0 = cchunk * CCH;

  __shared__ float wl[CIN * 16][CCH];
  for (int i = threadIdx.x; i < CIN * 16 * CCH; i += 256) {
    int cc = i % CCH;
    int tap = i / CCH;
    int ci = tap >> 4;
    int kk = tap & 15;
    wl[tap][cc] = w[((size_t)ci * COUT + (co0 + cc)) * 16 + kk];
  }
  __syncthreads();

  int t = threadIdx.x;
  int sx = t % WIN;
  int syb = ptile * ROWS_PER_TILE + t / WIN;
  int ky0 = (py + 1) & 1, kx0 = (px + 1) & 1;
  int ay = (py + 1 - ky0) >> 1;
  int ax = (px + 1 - kx0) >> 1;

  float acc[4][CCH];
#pragma unroll
  for (int j = 0; j < 4; j++)
#pragma unroll
    for (int c = 0; c < CCH; c++) acc[j][c] = 0.f;

  const float* xn = x + (size_t)n * CIN * HIN * WIN;

  for (int ci = 0; ci < CIN; ci++) {
    const float* xc = xn + (size_t)ci * HIN * WIN;
#pragma unroll
    for (int kyi = 0; kyi < 2; kyi++) {
      int ky = ky0 + 2 * kyi;
      int dy = ay - kyi;
#pragma unroll
      for (int kxi = 0; kxi < 2; kxi++) {
        int kx = kx0 + 2 * kxi;
        int ix = sx + ax - kxi;
        bool xok = (unsigned)ix < WIN;
        float xv[4];
#pragma unroll
        for (int j = 0; j < 4; j++) {
          int iy = syb + j * RSTEP + dy;
          xv[j] = (xok && (unsigned)iy < HIN) ? xc[iy * WIN + ix] : 0.f;
        }
        const float* wr = &wl[ci * 16 + ky * 4 + kx][0];
        if constexpr (CCH >= 4) {
#pragma unroll
          for (int c = 0; c < CCH; c += 4) {
            float4 wv = *(const float4*)(wr + c);
#pragma unroll
            for (int j = 0; j < 4; j++) {
              acc[j][c + 0] = fmaf(xv[j], wv.x, acc[j][c + 0]);
              acc[j][c + 1] = fmaf(xv[j], wv.y, acc[j][c + 1]);
              acc[j][c + 2] = fmaf(xv[j], wv.z, acc[j][c + 2]);
              acc[j][c + 3] = fmaf(xv[j], wv.w, acc[j][c + 3]);
            }
          }
        } else {
          float wv = wr[0];
#pragma unroll
          for (int j = 0; j < 4; j++) acc[j][0] = fmaf(xv[j], wv, acc[j][0]);
        }
      }
    }
  }

#pragma unroll
  for (int j = 0; j < 4; j++) {
    int sy = syb + j * RSTEP;
    int oy = 2 * sy + py;
    int ox = 2 * sx + px;
    float* op = out + (((size_t)n * COUT + co0) * HOUT + oy) * WOUT + ox;
#pragma unroll
    for (int c = 0; c < CCH; c++) {
      float v = acc[j][c] + bias[co0 + c];
      if (RELU) v = fmaxf(v, 0.f);
      if (SIG) v = 1.f / (1.f + expf(-v));
      op[(size_t)c * HOUT * WOUT] = v;
    }
  }
}

// ---------------------------------------------------------------------------
__global__ void cbn_prep(const float* __restrict__ cb, float* __restrict__ cbn) {
#pragma clang fp contract(off)
  int k = blockIdx.x * 256 + threadIdx.x;
  if (k < 512) {
    float m[32];
#pragma unroll
    for (int d = 0; d < 32; d++) {
      float c = cb[k * 32 + d];
      m[d] = c * c;
    }
    float r[8];
#pragma unroll
    for (int j = 0; j < 8; j++)
      r[j] = ((m[j] + m[8 + j]) + m[16 + j]) + m[24 + j];
    cbn[k] = ((r[0] + r[1]) + (r[2] + r[3])) + ((r[4] + r[5]) + (r[6] + r[7]));
  }
}

// ---------------------------------------------------------------------------
// VQ: np-exact distance arithmetic (round-4 verified). 2 pixels/thread.
// ---------------------------------------------------------------------------
__global__ __launch_bounds__(256, 2)
void vq_kernel(const float* __restrict__ z, const float* __restrict__ cb,
               const float* __restrict__ cbn, float* __restrict__ qz,
               float* __restrict__ loss) {
  __shared__ float cbl[512][32];
  int tid = threadIdx.x;
  for (int i = tid; i < 16384; i += 256) ((float*)cbl)[i] = cb[i];
  __syncthreads();

  int n = blockIdx.x >> 1;
  int p0 = (blockIdx.x & 1) * 512 + tid;
  int p1 = p0 + 256;
  const float* zn = z + (size_t)n * 32 * 1024;

  float z0[32], z1[32];
#pragma unroll
  for (int d = 0; d < 32; d++) {
    z0[d] = zn[(size_t)d * 1024 + p0];
    z1[d] = zn[(size_t)d * 1024 + p1];
  }

  float zz0, zz1;
  {
#pragma clang fp contract(off)
    float m0[32], m1[32];
#pragma unroll
    for (int d = 0; d < 32; d++) {
      m0[d] = z0[d] * z0[d];
      m1[d] = z1[d] * z1[d];
    }
    float r0[8], r1[8];
#pragma unroll
    for (int j = 0; j < 8; j++) {
      r0[j] = ((m0[j] + m0[8 + j]) + m0[16 + j]) + m0[24 + j];
      r1[j] = ((m1[j] + m1[8 + j]) + m1[16 + j]) + m1[24 + j];
    }
    zz0 = ((r0[0] + r0[1]) + (r0[2] + r0[3])) + ((r0[4] + r0[5]) + (r0[6] + r0[7]));
    zz1 = ((r1[0] + r1[1]) + (r1[2] + r1[3])) + ((r1[4] + r1[5]) + (r1[6] + r1[7]));
  }

  float best0 = 3.4e38f, best1 = 3.4e38f;
  int bk0 = 0, bk1 = 0;
  for (int k4 = 0; k4 < 512; k4 += 4) {
    float4 cn = *(const float4*)(cbn + k4);
    float da[4], db[4];
#pragma unroll
    for (int u = 0; u < 4; u++) { da[u] = 0.f; db[u] = 0.f; }
#pragma unroll
    for (int d = 0; d < 32; d += 4) {
#pragma unroll
      for (int u = 0; u < 4; u++) {
        float4 c = *(const float4*)&cbl[k4 + u][d];
        float a = da[u], b = db[u];
        a = fmaf(z0[d + 0], c.x, a);
        a = fmaf(z0[d + 1], c.y, a);
        a = fmaf(z0[d + 2], c.z, a);
        a = fmaf(z0[d + 3], c.w, a);
        b = fmaf(z1[d + 0], c.x, b);
        b = fmaf(z1[d + 1], c.y, b);
        b = fmaf(z1[d + 2], c.z, b);
        b = fmaf(z1[d + 3], c.w, b);
        da[u] = a; db[u] = b;
      }
    }
#pragma unroll
    for (int u = 0; u < 4; u++) {
      float cnu = (u == 0) ? cn.x : (u == 1) ? cn.y : (u == 2) ? cn.z : cn.w;
      float s0, s1;
      {
#pragma clang fp contract(off)
        s0 = (zz0 + cnu) - 2.f * da[u];
        s1 = (zz1 + cnu) - 2.f * db[u];
      }
      int k = k4 + u;
      if (s0 < best0) { best0 = s0; bk0 = k; }
      if (s1 < best1) { best1 = s1; bk1 = k; }
    }
  }

  float lsum = 0.f;
  float* qn = qz + (size_t)n * 32 * 1024;
#pragma unroll
  for (int d = 0; d < 32; d += 4) {
#pragma clang fp contract(off)
    float4 q0 = *(const float4*)(cb + bk0 * 32 + d);
    float4 q1 = *(const float4*)(cb + bk1 * 32 + d);
    float e;
    e = q0.x - z0[d + 0]; lsum = fmaf(e, e, lsum);
    e = q0.y - z0[d + 1]; lsum = fmaf(e, e, lsum);
    e = q0.z - z0[d + 2]; lsum = fmaf(e, e, lsum);
    e = q0.w - z0[d + 3]; lsum = fmaf(e, e, lsum);
    e = q1.x - z1[d + 0]; lsum = fmaf(e, e, lsum);
    e = q1.y - z1[d + 1]; lsum = fmaf(e, e, lsum);
    e = q1.z - z1[d + 2]; lsum = fmaf(e, e, lsum);
    e = q1.w - z1[d + 3]; lsum = fmaf(e, e, lsum);
    qn[(size_t)(d + 0) * 1024 + p0] = z0[d + 0] + (q0.x - z0[d + 0]);
    qn[(size_t)(d + 1) * 1024 + p0] = z0[d + 1] + (q0.y - z0[d + 1]);
    qn[(size_t)(d + 2) * 1024 + p0] = z0[d + 2] + (q0.z - z0[d + 2]);
    qn[(size_t)(d + 3) * 1024 + p0] = z0[d + 3] + (q0.w - z0[d + 3]);
    qn[(size_t)(d + 0) * 1024 + p1] = z1[d + 0] + (q1.x - z1[d + 0]);
    qn[(size_t)(d + 1) * 1024 + p1] = z1[d + 1] + (q1.y - z1[d + 1]);
    qn[(size_t)(d + 2) * 1024 + p1] = z1[d + 2] + (q1.z - z1[d + 2]);
    qn[(size_t)(d + 3) * 1024 + p1] = z1[d + 3] + (q1.w - z1[d + 3]);
  }

#pragma unroll
  for (int off = 32; off; off >>= 1) lsum += __shfl_down(lsum, off, 64);
  if ((tid & 63) == 0) atomicAdd(loss, lsum);
}

__global__ void finalize_loss(const float* __restrict__ loss, float* __restrict__ out) {
  if (threadIdx.x == 0) {
    float m = loss[0] / 8388608.f;
    out[0] = m + 0.26f * m;
  }
}

// ---------------------------------------------------------------------------
// Pipeline; chunk count chosen from ws_size (constant across calls => graph-
// safe). Full batch needs (33.5M + 16.8M + 513) fl = 201.3 MB.
// ---------------------------------------------------------------------------
extern "C" void kernel_launch(void* const* d_in, const int* in_sizes, int n_in,
                              void* d_out, int out_size, void* d_ws, size_t ws_size,
                              hipStream_t stream) {
  (void)in_sizes; (void)n_in; (void)out_size;
  const float* x   = (const float*)d_in[0];
  const float* ew1 = (const float*)d_in[1];
  const float* eb1 = (const float*)d_in[2];
  const float* ew2 = (const float*)d_in[3];
  const float* eb2 = (const float*)d_in[4];
  const float* ew3 = (const float*)d_in[5];
  const float* eb3 = (const float*)d_in[6];
  const float* ew4 = (const float*)d_in[7];
  const float* eb4 = (const float*)d_in[8];
  const float* cb  = (const float*)d_in[9];
  const float* dw1 = (const float*)d_in[10];
  const float* db1 = (const float*)d_in[11];
  const float* tw1 = (const float*)d_in[12];
  const float* tb1 = (const float*)d_in[13];
  const float* tw2 = (const float*)d_in[14];
  const float* tb2 = (const float*)d_in[15];
  float* out = (float*)d_out;

  auto need = [](size_t c) -> size_t { return (c * 131072 + c * 65536 + 513) * 4; };
  int nchunks = 4;
  if (ws_size >= need(256)) nchunks = 1;
  else if (ws_size >= need(128)) nchunks = 2;
  int chunk = 256 / nchunks;

  float* ws = (float*)d_ws;
  float* A = ws;
  float* B = A + (size_t)chunk * 131072;
  float* cbn = B + (size_t)chunk * 65536;
  float* lossacc = cbn + 512;

  float* h1 = A;
  float* h2 = B;
  float* h3 = A;
  float* z  = A + (size_t)chunk * 65536;
  float* qz = A + (size_t)chunk * 98304;
  float* d1 = B;
  float* d2 = A;

  cbn_prep<<<2, 256, 0, stream>>>(cb, cbn);
  (void)hipMemsetAsync(lossacc, 0, 4, stream);

  for (int c = 0; c < nchunks; c++) {
    const float* xc = x + (size_t)c * chunk * 128 * 128;
    float* outc = out + (size_t)c * chunk * 128 * 128;

    conv_fwd<1, 32, 4, 2, 1, 128, 128, 64, 64, true, 16>
        <<<chunk * 4 * 2, 256, 0, stream>>>(xc, ew1, eb1, h1);
    conv4x4s2_lds<32, 64, 16>
        <<<chunk * 4, 256, 0, stream>>>(h1, ew2, eb2, h2);
    conv3x3_lds<64, 64, 16>
        <<<chunk * 4, 256, 0, stream>>>(h2, ew3, eb3, h3);
    conv_fwd<64, 32, 1, 1, 0, 32, 32, 32, 32, false, 16>
        <<<chunk * 2, 256, 0, stream>>>(h3, ew4, eb4, z);

    vq_kernel<<<chunk * 2, 256, 0, stream>>>(z, cb, cbn, qz, lossacc);

    conv3x3_lds<32, 64, 16>
        <<<chunk * 4, 256, 0, stream>>>(qz, dw1, db1, d1);
    convt_lds<64, 32, 16>
        <<<chunk * 4 * 2, 256, 0, stream>>>(d1, tw1, tb1, d2);
    convt_fwd<32, 1, 64, 64, false, true, 1>
        <<<chunk * 4 * 4 * 1, 256, 0, stream>>>(d2, tw2, tb2, outc);
  }

  finalize_loss<<<1, 64, 0, stream>>>(lossacc, out + 4194304);
}